// Round 1
// 1196.760 us; speedup vs baseline: 1.0160x; 1.0160x over previous
//
#include <hip/hip_runtime.h>

// SigLipAttention: B=32 S=576 H=12 D=64 E=768
// out  = fp32 [B,S,E]            @ d_out
// attn = fp32 [B,H,S,S] softmax  @ d_out + 14155776
//
// Pipeline (R1: softmax+PV fused, V pre-transposed):
//  cvt_split  : X, q_w, k_w -> bf16 hi/lo ; v_w, o_w -> bf16 hi
//  gemm128    : q = X@q_w^T+b (split, out hi/lo), k likewise,
//               v (plain, bf16, written TRANSPOSED as [b,h,d,s])
//  attn_pv    : scores (split MFMA) -> softmax fp32 -> attn (nontemporal, d_out)
//               -> P bf16 in LDS -> PV MFMA -> out_pre (bf16)
//  gemm128    : out = out_pre@o_w^T + o_b (fp32 -> d_out)

#define B_ 32
#define S_ 576
#define H_ 12
#define D_ 64
#define E_ 768
#define M_ (B_ * S_)          // 18432

typedef __attribute__((ext_vector_type(8))) short bf16x8;
typedef __attribute__((ext_vector_type(4))) float f32x4;
typedef __attribute__((ext_vector_type(4))) unsigned short u16x4;
typedef __attribute__((ext_vector_type(8))) unsigned short u16x8;

#define MFMA16(a, b, c) __builtin_amdgcn_mfma_f32_16x16x32_bf16(a, b, c, 0, 0, 0)

__device__ __forceinline__ unsigned short f2bf(float x) {
  union { float f; unsigned u; } v; v.f = x;
  unsigned r = v.u + 0x7fffu + ((v.u >> 16) & 1u);   // RNE
  return (unsigned short)(r >> 16);
}
__device__ __forceinline__ float bf2f(unsigned short h) {
  union { unsigned u; float f; } v; v.u = ((unsigned)h) << 16; return v.f;
}

// ---------------- fp32 -> bf16 hi (+ optional lo) ----------------
__global__ __launch_bounds__(256) void cvt_split(const float* __restrict__ in,
                                                 unsigned short* __restrict__ hi,
                                                 unsigned short* __restrict__ lo,
                                                 int n4) {
  int i = blockIdx.x * 256 + threadIdx.x;
  if (i >= n4) return;
  float4 x = ((const float4*)in)[i];
  u16x4 h;
  h[0] = f2bf(x.x); h[1] = f2bf(x.y); h[2] = f2bf(x.z); h[3] = f2bf(x.w);
  ((u16x4*)hi)[i] = h;
  if (lo) {
    u16x4 l;
    l[0] = f2bf(x.x - bf2f(h[0])); l[1] = f2bf(x.y - bf2f(h[1]));
    l[2] = f2bf(x.z - bf2f(h[2])); l[3] = f2bf(x.w - bf2f(h[3]));
    ((u16x4*)lo)[i] = l;
  }
}

// ---------------- NT GEMM: C[m,n] = sum_k A[m,k]*B[n,k] + bias[n] ----------------
// A,B given as bf16 hi (and lo when SPLIT). 128x128 tile, BK=32, 256 threads.
// OUT_MODE: 0 = fp32 C0 ; 1 = bf16 C0 ; 2 = bf16 split C0(hi)/C1(lo)
//           3 = bf16 C0 written transposed as V^T [b,h,d,s]  (m = b*576+s, n = h*64+d)
template <bool SPLIT, int OUT_MODE>
__global__ __launch_bounds__(256)
void gemm128(const unsigned short* __restrict__ Ahg, const unsigned short* __restrict__ Alg,
             const unsigned short* __restrict__ Bhg, const unsigned short* __restrict__ Blg,
             const float* __restrict__ bias, void* __restrict__ C0, void* __restrict__ C1,
             int Kd, int lda, int ldb, int ldc) {
  constexpr int BM = 128, BN = 128, BK = 32, LSTR = BK + 8;  // +8 halves pad
  __shared__ __attribute__((aligned(16))) unsigned short Ah[BM * LSTR];
  __shared__ __attribute__((aligned(16))) unsigned short Bh[BN * LSTR];
  __shared__ __attribute__((aligned(16))) unsigned short Al[SPLIT ? BM * LSTR : 8];
  __shared__ __attribute__((aligned(16))) unsigned short Bl[SPLIT ? BN * LSTR : 8];

  const int tid = threadIdx.x, lane = tid & 63, wv = tid >> 6;
  const int wm = (wv & 1) * 64, wn = (wv >> 1) * 64;
  const long m0 = (long)blockIdx.y * BM, n0 = (long)blockIdx.x * BN;
  const int fr = lane & 15, g8 = (lane >> 4) * 8;

  f32x4 acc[4][4] = {};

  for (int kt = 0; kt < Kd; kt += BK) {
    __syncthreads();
    for (int i = tid; i < BM * BK / 8; i += 256) {  // 512 chunks of 8 halves
      int row = i >> 2, c8 = (i & 3) * 8;
      *(u16x8*)&Ah[row * LSTR + c8] = *(const u16x8*)(Ahg + (m0 + row) * lda + kt + c8);
      *(u16x8*)&Bh[row * LSTR + c8] = *(const u16x8*)(Bhg + (n0 + row) * ldb + kt + c8);
      if (SPLIT) {
        *(u16x8*)&Al[row * LSTR + c8] = *(const u16x8*)(Alg + (m0 + row) * lda + kt + c8);
        *(u16x8*)&Bl[row * LSTR + c8] = *(const u16x8*)(Blg + (n0 + row) * ldb + kt + c8);
      }
    }
    __syncthreads();
    bf16x8 ah[4], bh[4], al[4], bl[4];
#pragma unroll
    for (int mi = 0; mi < 4; ++mi) {
      ah[mi] = *(const bf16x8*)&Ah[(wm + mi * 16 + fr) * LSTR + g8];
      if (SPLIT) al[mi] = *(const bf16x8*)&Al[(wm + mi * 16 + fr) * LSTR + g8];
    }
#pragma unroll
    for (int ni = 0; ni < 4; ++ni) {
      bh[ni] = *(const bf16x8*)&Bh[(wn + ni * 16 + fr) * LSTR + g8];
      if (SPLIT) bl[ni] = *(const bf16x8*)&Bl[(wn + ni * 16 + fr) * LSTR + g8];
    }
#pragma unroll
    for (int mi = 0; mi < 4; ++mi)
#pragma unroll
      for (int ni = 0; ni < 4; ++ni) {
        acc[mi][ni] = MFMA16(ah[mi], bh[ni], acc[mi][ni]);
        if (SPLIT) {
          acc[mi][ni] = MFMA16(ah[mi], bl[ni], acc[mi][ni]);
          acc[mi][ni] = MFMA16(al[mi], bh[ni], acc[mi][ni]);
        }
      }
  }

#pragma unroll
  for (int mi = 0; mi < 4; ++mi)
#pragma unroll
    for (int ni = 0; ni < 4; ++ni) {
      long col = n0 + wn + ni * 16 + fr;
      long rb = m0 + wm + mi * 16 + (lane >> 4) * 4;
      float bv = bias ? bias[col] : 0.f;
#pragma unroll
      for (int r = 0; r < 4; ++r) {
        float v = acc[mi][ni][r] + bv;
        long idx = (rb + r) * ldc + col;
        if (OUT_MODE == 0) {
          ((float*)C0)[idx] = v;
        } else if (OUT_MODE == 1) {
          ((unsigned short*)C0)[idx] = f2bf(v);
        } else if (OUT_MODE == 2) {
          unsigned short hh = f2bf(v);
          ((unsigned short*)C0)[idx] = hh;
          ((unsigned short*)C1)[idx] = f2bf(v - bf2f(hh));
        } else {  // OUT_MODE == 3 : V^T [b,h,d,s]
          long m = rb + r;
          int bb = (int)(m / S_);
          int ss = (int)(m - (long)bb * S_);
          int hh2 = (int)(col >> 6), dd = (int)(col & 63);
          ((unsigned short*)C0)[(((long)bb * H_ + hh2) * D_ + dd) * S_ + ss] = f2bf(v);
        }
      }
    }
}

// ---------------- fused: scores -> softmax -> attn (fp32) + PV -> out_pre (bf16) ------
// grid (18, 12, 32) = (qtile, h, b). 32 q-rows per block, scores in registers.
// Scores: wave wv: rows (wv&1)*16..+16 ; cols (per 64-col k-tile) (wv>>1)*32..+32.
// PV:     wave wv: rows (wv&1)*16..+16 ; d-cols (wv>>1)*32..+32.  P via LDS (bf16),
//         V tiles staged from pre-transposed V^T [b,h,d,s].
__global__ __launch_bounds__(256)
void attn_pv(const unsigned short* __restrict__ qh, const unsigned short* __restrict__ ql,
             const unsigned short* __restrict__ kh, const unsigned short* __restrict__ kl,
             const unsigned short* __restrict__ vt,
             float* __restrict__ attn, unsigned short* __restrict__ out_pre) {
  constexpr int LQ = 72;   // 64 + 8 pad (halves)
  constexpr int LP = 584;  // 576 + 8 pad (halves): row stride 1168B -> <=2-way bank alias
  __shared__ __attribute__((aligned(16))) unsigned short qhl[32 * LQ], qll[32 * LQ];
  __shared__ __attribute__((aligned(16))) unsigned short khl[64 * LQ], kll[64 * LQ];
  __shared__ __attribute__((aligned(16))) unsigned short P_lds[32 * LP];
  __shared__ float redm[2][32], reds[2][32];
  unsigned short* Vt = kll;  // kll dead after scores phase; reuse for V tiles (64*LQ)

  const int tid = threadIdx.x, lane = tid & 63, wv = tid >> 6;
  const int qt = blockIdx.x, h = blockIdx.y, b = blockIdx.z;
  const int fr = lane & 15, gq = lane >> 4;
  const int mg = (wv & 1), ch = (wv >> 1);

  // stage q tile: 32 rows x 64 halves (hi+lo), one u16x8 per thread per array
  {
    int row = tid >> 3, c8 = (tid & 7) * 8;
    long qb = ((long)(b * S_ + qt * 32 + row)) * E_ + h * 64 + c8;
    *(u16x8*)&qhl[row * LQ + c8] = *(const u16x8*)(qh + qb);
    *(u16x8*)&qll[row * LQ + c8] = *(const u16x8*)(ql + qb);
  }
  __syncthreads();
  bf16x8 qa_h[2], qa_l[2];
#pragma unroll
  for (int kc = 0; kc < 2; ++kc) {
    qa_h[kc] = *(const bf16x8*)&qhl[(mg * 16 + fr) * LQ + kc * 32 + gq * 8];
    qa_l[kc] = *(const bf16x8*)&qll[(mg * 16 + fr) * LQ + kc * 32 + gq * 8];
  }

  f32x4 acc[9][2] = {};
  for (int kt = 0; kt < 9; ++kt) {
    __syncthreads();
    for (int i = tid; i < 512; i += 256) {
      int row = i >> 3, c8 = (i & 7) * 8;
      long kb = ((long)(b * S_ + kt * 64 + row)) * E_ + h * 64 + c8;
      *(u16x8*)&khl[row * LQ + c8] = *(const u16x8*)(kh + kb);
      *(u16x8*)&kll[row * LQ + c8] = *(const u16x8*)(kl + kb);
    }
    __syncthreads();
#pragma unroll
    for (int kc = 0; kc < 2; ++kc) {
#pragma unroll
      for (int nf = 0; nf < 2; ++nf) {
        bf16x8 b_h = *(const bf16x8*)&khl[(ch * 32 + nf * 16 + fr) * LQ + kc * 32 + gq * 8];
        bf16x8 b_l = *(const bf16x8*)&kll[(ch * 32 + nf * 16 + fr) * LQ + kc * 32 + gq * 8];
        acc[kt][nf] = MFMA16(qa_h[kc], b_h, acc[kt][nf]);
        acc[kt][nf] = MFMA16(qa_h[kc], b_l, acc[kt][nf]);
        acc[kt][nf] = MFMA16(qa_l[kc], b_h, acc[kt][nf]);
      }
    }
  }

  // ---- softmax over 576 cols, rows distributed: lane holds rows mg*16+gq*4+r,
  // cols kt*64 + ch*32 + nf*16 + fr  (x0.125 scale applied here)
  const float SC = 0.125f;
  float M[4], Sv[4];
#pragma unroll
  for (int r = 0; r < 4; ++r) {
    float pm = -1e30f;
#pragma unroll
    for (int kt = 0; kt < 9; ++kt)
#pragma unroll
      for (int nf = 0; nf < 2; ++nf) pm = fmaxf(pm, acc[kt][nf][r] * SC);
    for (int off = 1; off < 16; off <<= 1) pm = fmaxf(pm, __shfl_xor(pm, off));
    M[r] = pm;
  }
  if (fr == 0) {
#pragma unroll
    for (int r = 0; r < 4; ++r) redm[ch][mg * 16 + gq * 4 + r] = M[r];
  }
  __syncthreads();
#pragma unroll
  for (int r = 0; r < 4; ++r)
    M[r] = fmaxf(redm[0][mg * 16 + gq * 4 + r], redm[1][mg * 16 + gq * 4 + r]);

#pragma unroll
  for (int r = 0; r < 4; ++r) {
    float ps = 0.f;
#pragma unroll
    for (int kt = 0; kt < 9; ++kt)
#pragma unroll
      for (int nf = 0; nf < 2; ++nf) {
        float e = __expf(acc[kt][nf][r] * SC - M[r]);
        acc[kt][nf][r] = e;
        ps += e;
      }
    for (int off = 1; off < 16; off <<= 1) ps += __shfl_xor(ps, off);
    Sv[r] = ps;
  }
  if (fr == 0) {
#pragma unroll
    for (int r = 0; r < 4; ++r) reds[ch][mg * 16 + gq * 4 + r] = Sv[r];
  }
  __syncthreads();
#pragma unroll
  for (int r = 0; r < 4; ++r)
    Sv[r] = 1.f / (reds[0][mg * 16 + gq * 4 + r] + reds[1][mg * 16 + gq * 4 + r]);

  // ---- write attn (fp32, nontemporal: never re-read) + P (bf16) to LDS
  float* out = attn + ((long)((b * H_ + h) * S_) + qt * 32) * S_;
#pragma unroll
  for (int kt = 0; kt < 9; ++kt)
#pragma unroll
    for (int nf = 0; nf < 2; ++nf)
#pragma unroll
      for (int r = 0; r < 4; ++r) {
        int row = mg * 16 + gq * 4 + r;
        int col = kt * 64 + ch * 32 + nf * 16 + fr;
        float val = acc[kt][nf][r] * Sv[r];
        __builtin_nontemporal_store(val, &out[(long)row * S_ + col]);
        P_lds[row * LP + col] = f2bf(val);
      }

  // ---- PV: out_pre[q, d] = sum_k P[q,k] * V[k,d], V^T tiles [d][k] from global
  const unsigned short* Vb = vt + ((long)(b * H_ + h)) * D_ * S_;
  f32x4 accp[2] = {};
  for (int kt2 = 0; kt2 < 9; ++kt2) {
    __syncthreads();  // P visible (iter 0) / prior Vt reads done (iters 1+)
    for (int i = tid; i < 512; i += 256) {
      int row = i >> 3, c8 = (i & 7) * 8;  // row = d (0..63), c8 = k-offset in tile
      *(u16x8*)&Vt[row * LQ + c8] = *(const u16x8*)(Vb + (long)row * S_ + kt2 * 64 + c8);
    }
    __syncthreads();
#pragma unroll
    for (int kc = 0; kc < 2; ++kc) {
      bf16x8 a = *(const bf16x8*)&P_lds[(mg * 16 + fr) * LP + kt2 * 64 + kc * 32 + gq * 8];
#pragma unroll
      for (int ni = 0; ni < 2; ++ni) {
        bf16x8 bv = *(const bf16x8*)&Vt[(ch * 32 + ni * 16 + fr) * LQ + kc * 32 + gq * 8];
        accp[ni] = MFMA16(a, bv, accp[ni]);
      }
    }
  }

#pragma unroll
  for (int ni = 0; ni < 2; ++ni)
#pragma unroll
    for (int r = 0; r < 4; ++r) {
      int row = mg * 16 + gq * 4 + r;   // q within tile
      int col = ch * 32 + ni * 16 + fr; // d
      out_pre[((long)b * S_ + qt * 32 + row) * E_ + h * 64 + col] = f2bf(accp[ni][r]);
    }
}

// ---------------- host ----------------
extern "C" void kernel_launch(void* const* d_in, const int* in_sizes, int n_in,
                              void* d_out, int out_size, void* d_ws, size_t ws_size,
                              hipStream_t stream) {
  const float* X = (const float*)d_in[0];
  const float* q_w = (const float*)d_in[1];
  const float* q_b = (const float*)d_in[2];
  const float* k_w = (const float*)d_in[3];
  const float* k_b = (const float*)d_in[4];
  const float* v_w = (const float*)d_in[5];
  const float* v_b = (const float*)d_in[6];
  const float* o_w = (const float*)d_in[7];
  const float* o_b = (const float*)d_in[8];

  const long NX = (long)M_ * E_;       // 14155776
  const long NW = (long)E_ * E_;       // 589824

  unsigned short* w = (unsigned short*)d_ws;
  unsigned short* Xhi = w;
  unsigned short* Xlo = Xhi + NX;
  unsigned short* qwh = Xlo + NX;
  unsigned short* qwl = qwh + NW;
  unsigned short* kwh = qwl + NW;
  unsigned short* kwl = kwh + NW;
  unsigned short* vwh = kwl + NW;
  unsigned short* owh = vwh + NW;
  unsigned short* Qhi = owh + NW;
  unsigned short* Qlo = Qhi + NX;
  unsigned short* Khi = Qlo + NX;
  unsigned short* Klo = Khi + NX;
  unsigned short* Vt  = Klo + NX;      // V^T [b,h,d,s] bf16
  unsigned short* Opre = Vt + NX;
  // total: 8*NX + 6*NW halves = 233,570,304 bytes of d_ws

  float* out_f = (float*)d_out;
  float* attn_f = (float*)d_out + NX;

  // 1) pre-split conversions
  cvt_split<<<dim3((NX / 4 + 255) / 256), dim3(256), 0, stream>>>(X, Xhi, Xlo, NX / 4);
  cvt_split<<<dim3((NW / 4 + 255) / 256), dim3(256), 0, stream>>>(q_w, qwh, qwl, NW / 4);
  cvt_split<<<dim3((NW / 4 + 255) / 256), dim3(256), 0, stream>>>(k_w, kwh, kwl, NW / 4);
  cvt_split<<<dim3((NW / 4 + 255) / 256), dim3(256), 0, stream>>>(v_w, vwh, nullptr, NW / 4);
  cvt_split<<<dim3((NW / 4 + 255) / 256), dim3(256), 0, stream>>>(o_w, owh, nullptr, NW / 4);

  dim3 gproj(E_ / 128, M_ / 128);  // (6, 144)
  // 2) projections (V written transposed for the fused PV)
  gemm128<true, 2><<<gproj, dim3(256), 0, stream>>>(Xhi, Xlo, qwh, qwl, q_b, Qhi, Qlo, E_, E_, E_, E_);
  gemm128<true, 2><<<gproj, dim3(256), 0, stream>>>(Xhi, Xlo, kwh, kwl, k_b, Khi, Klo, E_, E_, E_, E_);
  gemm128<false, 3><<<gproj, dim3(256), 0, stream>>>(Xhi, nullptr, vwh, nullptr, v_b, Vt, nullptr, E_, E_, E_, E_);

  // 3) scores + softmax -> attn ; fused PV -> out_pre (bf16)
  attn_pv<<<dim3(S_ / 32, H_, B_), dim3(256), 0, stream>>>(Qhi, Qlo, Khi, Klo, Vt, attn_f, Opre);

  // 4) O projection -> out (fp32)
  gemm128<false, 0><<<gproj, dim3(256), 0, stream>>>(Opre, nullptr, owh, nullptr, o_b, out_f, nullptr, E_, E_, E_, E_);
}

// Round 2
// 1162.835 us; speedup vs baseline: 1.0456x; 1.0292x over previous
//
#include <hip/hip_runtime.h>

// SigLipAttention: B=32 S=576 H=12 D=64 E=768
// out  = fp32 [B,S,E]            @ d_out
// attn = fp32 [B,H,S,S] softmax  @ d_out + 14155776
//
// R2: gemm128 staging via global_load_lds (w=16, linear LDS, m97 structure);
//     attn_pv LDS aliased (P over dead q/k buffers) -> 47KB -> 3 blocks/CU;
//     attn stores no longer nontemporal (L2 merges lines).

#define B_ 32
#define S_ 576
#define H_ 12
#define D_ 64
#define E_ 768
#define M_ (B_ * S_)          // 18432

typedef __attribute__((ext_vector_type(8))) short bf16x8;
typedef __attribute__((ext_vector_type(4))) float f32x4;
typedef __attribute__((ext_vector_type(4))) unsigned short u16x4;
typedef __attribute__((ext_vector_type(8))) unsigned short u16x8;

#define MFMA16(a, b, c) __builtin_amdgcn_mfma_f32_16x16x32_bf16(a, b, c, 0, 0, 0)

__device__ __forceinline__ unsigned short f2bf(float x) {
  union { float f; unsigned u; } v; v.f = x;
  unsigned r = v.u + 0x7fffu + ((v.u >> 16) & 1u);   // RNE
  return (unsigned short)(r >> 16);
}
__device__ __forceinline__ float bf2f(unsigned short h) {
  union { unsigned u; float f; } v; v.u = ((unsigned)h) << 16; return v.f;
}

// async global(16B/lane) -> LDS. Dest = lds base + lane*16 (wave-uniform base).
__device__ __forceinline__ void gload16(unsigned short* lds, const unsigned short* g) {
  __builtin_amdgcn_global_load_lds(
      (const __attribute__((address_space(1))) unsigned int*)g,
      (__attribute__((address_space(3))) unsigned int*)lds, 16, 0, 0);
}

// ---------------- fp32 -> bf16 hi (+ optional lo) ----------------
__global__ __launch_bounds__(256) void cvt_split(const float* __restrict__ in,
                                                 unsigned short* __restrict__ hi,
                                                 unsigned short* __restrict__ lo,
                                                 int n4) {
  int i = blockIdx.x * 256 + threadIdx.x;
  if (i >= n4) return;
  float4 x = ((const float4*)in)[i];
  u16x4 h;
  h[0] = f2bf(x.x); h[1] = f2bf(x.y); h[2] = f2bf(x.z); h[3] = f2bf(x.w);
  ((u16x4*)hi)[i] = h;
  if (lo) {
    u16x4 l;
    l[0] = f2bf(x.x - bf2f(h[0])); l[1] = f2bf(x.y - bf2f(h[1]));
    l[2] = f2bf(x.z - bf2f(h[2])); l[3] = f2bf(x.w - bf2f(h[3]));
    ((u16x4*)lo)[i] = l;
  }
}

// ---------------- NT GEMM: C[m,n] = sum_k A[m,k]*B[n,k] + bias[n] ----------------
// A,B given as bf16 hi (and lo when SPLIT). 128x128 tile, BK=32, 256 threads.
// Staging: global_load_lds width=16, linear LDS [128][32] (m97 structure).
// OUT_MODE: 0 = fp32 C0 ; 1 = bf16 C0 ; 2 = bf16 split C0(hi)/C1(lo)
//           3 = bf16 C0 written transposed as V^T [b,h,d,s]  (m = b*576+s, n = h*64+d)
template <bool SPLIT, int OUT_MODE>
__global__ __launch_bounds__(256)
void gemm128(const unsigned short* __restrict__ Ahg, const unsigned short* __restrict__ Alg,
             const unsigned short* __restrict__ Bhg, const unsigned short* __restrict__ Blg,
             const float* __restrict__ bias, void* __restrict__ C0, void* __restrict__ C1,
             int Kd, int lda, int ldb, int ldc) {
  constexpr int BM = 128, BN = 128, BK = 32;   // linear LDS, no pad (gload_lds dest)
  __shared__ __attribute__((aligned(16))) unsigned short Ah[BM * BK];
  __shared__ __attribute__((aligned(16))) unsigned short Bh[BN * BK];
  __shared__ __attribute__((aligned(16))) unsigned short Al[SPLIT ? BM * BK : 8];
  __shared__ __attribute__((aligned(16))) unsigned short Bl[SPLIT ? BN * BK : 8];

  const int tid = threadIdx.x, lane = tid & 63, wv = tid >> 6;
  const int wm = (wv & 1) * 64, wn = (wv >> 1) * 64;
  const long m0 = (long)blockIdx.y * BM, n0 = (long)blockIdx.x * BN;
  const int fr = lane & 15, g8 = (lane >> 4) * 8;
  // staging lane mapping: chunk = 16 rows (1KB); lane covers row lane>>2, col8 (lane&3)*8
  const int srow = lane >> 2, sc8 = (lane & 3) * 8;

  f32x4 acc[4][4] = {};

  for (int kt = 0; kt < Kd; kt += BK) {
    __syncthreads();
#pragma unroll
    for (int c = 0; c < 2; ++c) {
      int chunk = wv * 2 + c;                 // 0..7, wave-uniform
      int row = chunk * 16 + srow;
      long ga = (m0 + row) * (long)lda + kt + sc8;
      long gb = (n0 + row) * (long)ldb + kt + sc8;
      gload16(&Ah[chunk * 512], Ahg + ga);
      gload16(&Bh[chunk * 512], Bhg + gb);
      if (SPLIT) {
        gload16(&Al[chunk * 512], Alg + ga);
        gload16(&Bl[chunk * 512], Blg + gb);
      }
    }
    __syncthreads();  // compiler drains vmcnt before barrier
    bf16x8 ah[4], bh[4], al[4], bl[4];
#pragma unroll
    for (int mi = 0; mi < 4; ++mi) {
      ah[mi] = *(const bf16x8*)&Ah[(wm + mi * 16 + fr) * BK + g8];
      if (SPLIT) al[mi] = *(const bf16x8*)&Al[(wm + mi * 16 + fr) * BK + g8];
    }
#pragma unroll
    for (int ni = 0; ni < 4; ++ni) {
      bh[ni] = *(const bf16x8*)&Bh[(wn + ni * 16 + fr) * BK + g8];
      if (SPLIT) bl[ni] = *(const bf16x8*)&Bl[(wn + ni * 16 + fr) * BK + g8];
    }
#pragma unroll
    for (int mi = 0; mi < 4; ++mi)
#pragma unroll
      for (int ni = 0; ni < 4; ++ni) {
        acc[mi][ni] = MFMA16(ah[mi], bh[ni], acc[mi][ni]);
        if (SPLIT) {
          acc[mi][ni] = MFMA16(ah[mi], bl[ni], acc[mi][ni]);
          acc[mi][ni] = MFMA16(al[mi], bh[ni], acc[mi][ni]);
        }
      }
  }

#pragma unroll
  for (int mi = 0; mi < 4; ++mi)
#pragma unroll
    for (int ni = 0; ni < 4; ++ni) {
      long col = n0 + wn + ni * 16 + fr;
      long rb = m0 + wm + mi * 16 + (lane >> 4) * 4;
      float bv = bias ? bias[col] : 0.f;
#pragma unroll
      for (int r = 0; r < 4; ++r) {
        float v = acc[mi][ni][r] + bv;
        long idx = (rb + r) * ldc + col;
        if (OUT_MODE == 0) {
          ((float*)C0)[idx] = v;
        } else if (OUT_MODE == 1) {
          ((unsigned short*)C0)[idx] = f2bf(v);
        } else if (OUT_MODE == 2) {
          unsigned short hh = f2bf(v);
          ((unsigned short*)C0)[idx] = hh;
          ((unsigned short*)C1)[idx] = f2bf(v - bf2f(hh));
        } else {  // OUT_MODE == 3 : V^T [b,h,d,s]
          long m = rb + r;
          int bb = (int)(m / S_);
          int ss = (int)(m - (long)bb * S_);
          int hh2 = (int)(col >> 6), dd = (int)(col & 63);
          ((unsigned short*)C0)[(((long)bb * H_ + hh2) * D_ + dd) * S_ + ss] = f2bf(v);
        }
      }
    }
}

// ---------------- fused: scores -> softmax -> attn (fp32) + PV -> out_pre (bf16) ------
// grid (18, 12, 32) = (qtile, h, b). 32 q-rows per block, scores in registers.
// LDS aliasing: P (32x584 bf16, 37.4KB) overlays qhl/qll/khl (all dead by the time P is
// written); kll (reused as Vt in PV) sits AFTER P. Total 46.6KB -> 3 blocks/CU.
__global__ __launch_bounds__(256)
void attn_pv(const unsigned short* __restrict__ qh, const unsigned short* __restrict__ ql,
             const unsigned short* __restrict__ kh, const unsigned short* __restrict__ kl,
             const unsigned short* __restrict__ vt,
             float* __restrict__ attn, unsigned short* __restrict__ out_pre) {
  constexpr int LQ = 72;   // 64 + 8 pad (halves)
  constexpr int LP = 584;  // 576 + 8 pad (halves)
  // layout (halves): qhl[0,2304) qll[2304,4608) khl[4608,9216) kll[18688,23296)
  //                  P  [0,18688)  (over qhl/qll/khl)           Vt = kll
  __shared__ __attribute__((aligned(16))) unsigned short smem[23296];
  __shared__ float redm[2][32], reds[2][32];
  unsigned short* qhl = smem;
  unsigned short* qll = smem + 2304;
  unsigned short* khl = smem + 4608;
  unsigned short* kll = smem + 18688;
  unsigned short* P_lds = smem;
  unsigned short* Vt = kll;

  const int tid = threadIdx.x, lane = tid & 63, wv = tid >> 6;
  const int qt = blockIdx.x, h = blockIdx.y, b = blockIdx.z;
  const int fr = lane & 15, gq = lane >> 4;
  const int mg = (wv & 1), ch = (wv >> 1);

  // stage q tile: 32 rows x 64 halves (hi+lo), one u16x8 per thread per array
  {
    int row = tid >> 3, c8 = (tid & 7) * 8;
    long qb = ((long)(b * S_ + qt * 32 + row)) * E_ + h * 64 + c8;
    *(u16x8*)&qhl[row * LQ + c8] = *(const u16x8*)(qh + qb);
    *(u16x8*)&qll[row * LQ + c8] = *(const u16x8*)(ql + qb);
  }
  __syncthreads();
  bf16x8 qa_h[2], qa_l[2];
#pragma unroll
  for (int kc = 0; kc < 2; ++kc) {
    qa_h[kc] = *(const bf16x8*)&qhl[(mg * 16 + fr) * LQ + kc * 32 + gq * 8];
    qa_l[kc] = *(const bf16x8*)&qll[(mg * 16 + fr) * LQ + kc * 32 + gq * 8];
  }

  f32x4 acc[9][2] = {};
  for (int kt = 0; kt < 9; ++kt) {
    __syncthreads();
    for (int i = tid; i < 512; i += 256) {
      int row = i >> 3, c8 = (i & 7) * 8;
      long kb = ((long)(b * S_ + kt * 64 + row)) * E_ + h * 64 + c8;
      *(u16x8*)&khl[row * LQ + c8] = *(const u16x8*)(kh + kb);
      *(u16x8*)&kll[row * LQ + c8] = *(const u16x8*)(kl + kb);
    }
    __syncthreads();
#pragma unroll
    for (int kc = 0; kc < 2; ++kc) {
#pragma unroll
      for (int nf = 0; nf < 2; ++nf) {
        bf16x8 b_h = *(const bf16x8*)&khl[(ch * 32 + nf * 16 + fr) * LQ + kc * 32 + gq * 8];
        bf16x8 b_l = *(const bf16x8*)&kll[(ch * 32 + nf * 16 + fr) * LQ + kc * 32 + gq * 8];
        acc[kt][nf] = MFMA16(qa_h[kc], b_h, acc[kt][nf]);
        acc[kt][nf] = MFMA16(qa_h[kc], b_l, acc[kt][nf]);
        acc[kt][nf] = MFMA16(qa_l[kc], b_h, acc[kt][nf]);
      }
    }
  }

  // ---- softmax over 576 cols, rows distributed: lane holds rows mg*16+gq*4+r,
  // cols kt*64 + ch*32 + nf*16 + fr  (x0.125 scale applied here)
  const float SC = 0.125f;
  float M[4], Sv[4];
#pragma unroll
  for (int r = 0; r < 4; ++r) {
    float pm = -1e30f;
#pragma unroll
    for (int kt = 0; kt < 9; ++kt)
#pragma unroll
      for (int nf = 0; nf < 2; ++nf) pm = fmaxf(pm, acc[kt][nf][r] * SC);
    for (int off = 1; off < 16; off <<= 1) pm = fmaxf(pm, __shfl_xor(pm, off));
    M[r] = pm;
  }
  if (fr == 0) {
#pragma unroll
    for (int r = 0; r < 4; ++r) redm[ch][mg * 16 + gq * 4 + r] = M[r];
  }
  __syncthreads();
#pragma unroll
  for (int r = 0; r < 4; ++r)
    M[r] = fmaxf(redm[0][mg * 16 + gq * 4 + r], redm[1][mg * 16 + gq * 4 + r]);

#pragma unroll
  for (int r = 0; r < 4; ++r) {
    float ps = 0.f;
#pragma unroll
    for (int kt = 0; kt < 9; ++kt)
#pragma unroll
      for (int nf = 0; nf < 2; ++nf) {
        float e = __expf(acc[kt][nf][r] * SC - M[r]);
        acc[kt][nf][r] = e;
        ps += e;
      }
    for (int off = 1; off < 16; off <<= 1) ps += __shfl_xor(ps, off);
    Sv[r] = ps;
  }
  if (fr == 0) {
#pragma unroll
    for (int r = 0; r < 4; ++r) reds[ch][mg * 16 + gq * 4 + r] = Sv[r];
  }
  __syncthreads();
#pragma unroll
  for (int r = 0; r < 4; ++r)
    Sv[r] = 1.f / (reds[0][mg * 16 + gq * 4 + r] + reds[1][mg * 16 + gq * 4 + r]);

  // ---- write attn (fp32) + P (bf16) to LDS (P overlays dead q/k buffers)
  float* out = attn + ((long)((b * H_ + h) * S_) + qt * 32) * S_;
#pragma unroll
  for (int kt = 0; kt < 9; ++kt)
#pragma unroll
    for (int nf = 0; nf < 2; ++nf)
#pragma unroll
      for (int r = 0; r < 4; ++r) {
        int row = mg * 16 + gq * 4 + r;
        int col = kt * 64 + ch * 32 + nf * 16 + fr;
        float val = acc[kt][nf][r] * Sv[r];
        out[(long)row * S_ + col] = val;
        P_lds[row * LP + col] = f2bf(val);
      }

  // ---- PV: out_pre[q, d] = sum_k P[q,k] * V[k,d], V^T tiles [d][k] from global
  const unsigned short* Vb = vt + ((long)(b * H_ + h)) * D_ * S_;
  f32x4 accp[2] = {};
  for (int kt2 = 0; kt2 < 9; ++kt2) {
    __syncthreads();  // P visible (iter 0) / prior Vt reads done (iters 1+)
    for (int i = tid; i < 512; i += 256) {
      int row = i >> 3, c8 = (i & 7) * 8;  // row = d (0..63), c8 = k-offset in tile
      *(u16x8*)&Vt[row * LQ + c8] = *(const u16x8*)(Vb + (long)row * S_ + kt2 * 64 + c8);
    }
    __syncthreads();
#pragma unroll
    for (int kc = 0; kc < 2; ++kc) {
      bf16x8 a = *(const bf16x8*)&P_lds[(mg * 16 + fr) * LP + kt2 * 64 + kc * 32 + gq * 8];
#pragma unroll
      for (int ni = 0; ni < 2; ++ni) {
        bf16x8 bv = *(const bf16x8*)&Vt[(ch * 32 + ni * 16 + fr) * LQ + kc * 32 + gq * 8];
        accp[ni] = MFMA16(a, bv, accp[ni]);
      }
    }
  }

#pragma unroll
  for (int ni = 0; ni < 2; ++ni)
#pragma unroll
    for (int r = 0; r < 4; ++r) {
      int row = mg * 16 + gq * 4 + r;   // q within tile
      int col = ch * 32 + ni * 16 + fr; // d
      out_pre[((long)b * S_ + qt * 32 + row) * E_ + h * 64 + col] = f2bf(accp[ni][r]);
    }
}

// ---------------- host ----------------
extern "C" void kernel_launch(void* const* d_in, const int* in_sizes, int n_in,
                              void* d_out, int out_size, void* d_ws, size_t ws_size,
                              hipStream_t stream) {
  const float* X = (const float*)d_in[0];
  const float* q_w = (const float*)d_in[1];
  const float* q_b = (const float*)d_in[2];
  const float* k_w = (const float*)d_in[3];
  const float* k_b = (const float*)d_in[4];
  const float* v_w = (const float*)d_in[5];
  const float* v_b = (const float*)d_in[6];
  const float* o_w = (const float*)d_in[7];
  const float* o_b = (const float*)d_in[8];

  const long NX = (long)M_ * E_;       // 14155776
  const long NW = (long)E_ * E_;       // 589824

  unsigned short* w = (unsigned short*)d_ws;
  unsigned short* Xhi = w;
  unsigned short* Xlo = Xhi + NX;
  unsigned short* qwh = Xlo + NX;
  unsigned short* qwl = qwh + NW;
  unsigned short* kwh = qwl + NW;
  unsigned short* kwl = kwh + NW;
  unsigned short* vwh = kwl + NW;
  unsigned short* owh = vwh + NW;
  unsigned short* Qhi = owh + NW;
  unsigned short* Qlo = Qhi + NX;
  unsigned short* Khi = Qlo + NX;
  unsigned short* Klo = Khi + NX;
  unsigned short* Vt  = Klo + NX;      // V^T [b,h,d,s] bf16
  unsigned short* Opre = Vt + NX;
  // total: 8*NX + 6*NW halves = 233,570,304 bytes of d_ws

  float* out_f = (float*)d_out;
  float* attn_f = (float*)d_out + NX;

  // 1) pre-split conversions
  cvt_split<<<dim3((NX / 4 + 255) / 256), dim3(256), 0, stream>>>(X, Xhi, Xlo, NX / 4);
  cvt_split<<<dim3((NW / 4 + 255) / 256), dim3(256), 0, stream>>>(q_w, qwh, qwl, NW / 4);
  cvt_split<<<dim3((NW / 4 + 255) / 256), dim3(256), 0, stream>>>(k_w, kwh, kwl, NW / 4);
  cvt_split<<<dim3((NW / 4 + 255) / 256), dim3(256), 0, stream>>>(v_w, vwh, nullptr, NW / 4);
  cvt_split<<<dim3((NW / 4 + 255) / 256), dim3(256), 0, stream>>>(o_w, owh, nullptr, NW / 4);

  dim3 gproj(E_ / 128, M_ / 128);  // (6, 144)
  // 2) projections (V written transposed for the fused PV)
  gemm128<true, 2><<<gproj, dim3(256), 0, stream>>>(Xhi, Xlo, qwh, qwl, q_b, Qhi, Qlo, E_, E_, E_, E_);
  gemm128<true, 2><<<gproj, dim3(256), 0, stream>>>(Xhi, Xlo, kwh, kwl, k_b, Khi, Klo, E_, E_, E_, E_);
  gemm128<false, 3><<<gproj, dim3(256), 0, stream>>>(Xhi, nullptr, vwh, nullptr, v_b, Vt, nullptr, E_, E_, E_, E_);

  // 3) scores + softmax -> attn ; fused PV -> out_pre (bf16)
  attn_pv<<<dim3(S_ / 32, H_, B_), dim3(256), 0, stream>>>(Qhi, Qlo, Khi, Klo, Vt, attn_f, Opre);

  // 4) O projection -> out (fp32)
  gemm128<false, 0><<<gproj, dim3(256), 0, stream>>>(Opre, nullptr, owh, nullptr, o_b, out_f, nullptr, E_, E_, E_, E_);
}